// Round 5
// baseline (643.562 us; speedup 1.0000x reference)
//
#include <hip/hip_runtime.h>
#include <hip/hip_bf16.h>

typedef __hip_bfloat16 bf16;
typedef __attribute__((ext_vector_type(8))) short short8;
typedef __attribute__((ext_vector_type(4))) float f32x4;

#define NB    8
#define LQ    5440
#define CCH   256
#define NHD   8
#define DFF   1024
#define TT    (NB * LQ)   // 43520 tokens

__device__ __forceinline__ float b2f(bf16 x) { return __bfloat162float(x); }
__device__ __forceinline__ bf16  f2b(float x) { return __float2bfloat16(x); }

// ---------------------------------------------------------------------------
// MFMA bf16 GEMM (round-3 proven structure: register-staged LDS, K+1 prefetch)
// A: M x K bf16 row-major. BT: N x K bf16 row-major (pre-transposed).
// 256 thr = 4 waves (2x2); tile 128x128; BK=32; 16x16x32 MFMA.
// ---------------------------------------------------------------------------
template <bool RELU, bool OUT_BF16>
__global__ __launch_bounds__(256) void mfma_gemm(
    const bf16* __restrict__ A, const bf16* __restrict__ BT,
    const float* __restrict__ bias, void* __restrict__ Cout,
    int M, int N, int K)
{
    __shared__ bf16 Abuf[128 * 32];
    __shared__ bf16 Bbuf[128 * 32];

    const int tid = threadIdx.x;
    const int wv = tid >> 6;
    const int ln = tid & 63;
    const int lane15 = ln & 15;
    const int quad = ln >> 4;
    const int m0 = blockIdx.y * 128;
    const int n0 = blockIdx.x * 128;
    const int wm = (wv >> 1) * 64;
    const int wn = (wv & 1) * 64;

    const int ar = tid >> 2;           // 0..63: row within 64-row half
    const int ac = (tid & 3) * 8;      // elem col (16B)

    f32x4 acc[4][4];
#pragma unroll
    for (int i = 0; i < 4; i++)
#pragma unroll
        for (int j = 0; j < 4; j++) acc[i][j] = (f32x4){0.f, 0.f, 0.f, 0.f};

    const int KT = K >> 5;
    short8 av[2], bv[2];
#pragma unroll
    for (int j = 0; j < 2; j++) {
        av[j] = *(const short8*)(A  + (size_t)(m0 + j * 64 + ar) * K + ac);
        bv[j] = *(const short8*)(BT + (size_t)(n0 + j * 64 + ar) * K + ac);
    }

    for (int kt = 0; kt < KT; kt++) {
        __syncthreads();
#pragma unroll
        for (int j = 0; j < 2; j++) {
            *(short8*)(Abuf + j * 2048 + tid * 8) = av[j];
            *(short8*)(Bbuf + j * 2048 + tid * 8) = bv[j];
        }
        __syncthreads();
        if (kt + 1 < KT) {
            const int k0 = (kt + 1) << 5;
#pragma unroll
            for (int j = 0; j < 2; j++) {
                av[j] = *(const short8*)(A  + (size_t)(m0 + j * 64 + ar) * K + k0 + ac);
                bv[j] = *(const short8*)(BT + (size_t)(n0 + j * 64 + ar) * K + k0 + ac);
            }
        }
        short8 afrag[4], bfrag[4];
#pragma unroll
        for (int i = 0; i < 4; i++)
            afrag[i] = *(const short8*)(Abuf + (wm + i * 16 + lane15) * 32 + quad * 8);
#pragma unroll
        for (int i = 0; i < 4; i++)
            bfrag[i] = *(const short8*)(Bbuf + (wn + i * 16 + lane15) * 32 + quad * 8);
#pragma unroll
        for (int mi = 0; mi < 4; mi++)
#pragma unroll
            for (int ni = 0; ni < 4; ni++)
                acc[mi][ni] = __builtin_amdgcn_mfma_f32_16x16x32_bf16(
                    afrag[mi], bfrag[ni], acc[mi][ni], 0, 0, 0);
    }

    // Epilogue. C/D layout: col = lane&15, row = quad*4 + reg.
#pragma unroll
    for (int ni = 0; ni < 4; ni++) {
        const int col = n0 + wn + ni * 16 + lane15;
        const float bi = bias[col];
#pragma unroll
        for (int mi = 0; mi < 4; mi++) {
#pragma unroll
            for (int r = 0; r < 4; r++) {
                const int row = m0 + wm + mi * 16 + quad * 4 + r;
                float v = acc[mi][ni][r] + bi;
                if (RELU) v = v > 0.f ? v : 0.f;
                if (OUT_BF16) ((bf16*)Cout)[(size_t)row * N + col] = f2b(v);
                else          ((float*)Cout)[(size_t)row * N + col] = v;
            }
        }
    }
}

// ---------------------------------------------------------------------------
// q_bf = bf16(src+pos); s_bf = bf16(src).
// ---------------------------------------------------------------------------
__global__ __launch_bounds__(256) void prep_tokens(
    const float* __restrict__ src, const float* __restrict__ pos,
    bf16* __restrict__ qb, bf16* __restrict__ sb)
{
    const int i = (blockIdx.x * 256 + threadIdx.x) * 4;
    const float4 s = *(const float4*)(src + i);
    const float4 p = *(const float4*)(pos + i);
    union { bf16 h[4]; ushort4 u; } qo, so;
    qo.h[0] = f2b(s.x + p.x); qo.h[1] = f2b(s.y + p.y);
    qo.h[2] = f2b(s.z + p.z); qo.h[3] = f2b(s.w + p.w);
    so.h[0] = f2b(s.x); so.h[1] = f2b(s.y); so.h[2] = f2b(s.z); so.h[3] = f2b(s.w);
    *(ushort4*)(qb + i) = qo.u;
    *(ushort4*)(sb + i) = so.u;
}

// ---------------------------------------------------------------------------
// All weight transposes + bias concat in ONE launch.
// WT[n*K+k] = bf16(W[k*N+n]) per segment.
// ---------------------------------------------------------------------------
__global__ __launch_bounds__(256) void prep_weights(
    const float* __restrict__ w_off, const float* __restrict__ w_attn,
    const float* __restrict__ w_val, const float* __restrict__ w_out,
    const float* __restrict__ w_ff1, const float* __restrict__ w_ff2,
    const float* __restrict__ b_off, const float* __restrict__ b_attn,
    bf16* __restrict__ wqkT, bf16* __restrict__ wvT, bf16* __restrict__ woT,
    bf16* __restrict__ wf1T, bf16* __restrict__ wf2T, float* __restrict__ bqk)
{
    int i = blockIdx.x * 256 + threadIdx.x;
    if (i < 65536) {                       // w_off: K=256,N=256
        wqkT[i] = f2b(w_off[(size_t)(i & 255) * 256 + (i >> 8)]);
    } else if ((i -= 65536) < 32768) {     // w_attn: K=256,N=128
        wqkT[65536 + i] = f2b(w_attn[(size_t)(i & 255) * 128 + (i >> 8)]);
    } else if ((i -= 32768) < 65536) {     // w_val
        wvT[i] = f2b(w_val[(size_t)(i & 255) * 256 + (i >> 8)]);
    } else if ((i -= 65536) < 65536) {     // w_out
        woT[i] = f2b(w_out[(size_t)(i & 255) * 256 + (i >> 8)]);
    } else if ((i -= 65536) < 262144) {    // w_ff1: K=256,N=1024 -> WT 1024x256
        wf1T[i] = f2b(w_ff1[(size_t)(i & 255) * 1024 + (i >> 8)]);
    } else if ((i -= 262144) < 262144) {   // w_ff2: K=1024,N=256 -> WT 256x1024
        wf2T[i] = f2b(w_ff2[(size_t)(i & 1023) * 256 + (i >> 10)]);
    } else if ((i -= 262144) < 384) {      // bias concat
        bqk[i] = (i < 256) ? b_off[i] : b_attn[i - 256];
    }
}

// ---------------------------------------------------------------------------
// Deformable sampling v3: ONE unit (token, head) per WAVE, no LDS.
// Phase A (all lanes, p = lane&15 redundant x4): fused softmax over 16 logits
//   + 4 corner (element-offset, weight) pairs kept in VGPRs.
// Phase B: 64 unrolled corners; (off,w) broadcast via v_readlane (SGPR),
//   gather load saddr-form, v_fmac_f32 acc, s_w, v_val. Lanes 32-63 duplicate
//   lanes 0-31 (same cache lines); only lanes<32 store.
// ---------------------------------------------------------------------------
__global__ __launch_bounds__(256) void msda_kernel(
    const bf16*  __restrict__ value,   // TT x 256 bf16
    const float* __restrict__ qk,      // TT x 384: off 0..255, logits 256..383
    const float* __restrict__ refp,    // TT x 8
    bf16* __restrict__ outb)           // TT x 256 bf16
{
    const int unit = blockIdx.x * 4 + (threadIdx.x >> 6);
    const int t = unit >> 3;
    const int h = unit & 7;
    const int lane = threadIdx.x & 63;
    const int d = lane & 31;

    // ---- Phase A ----
    const int p = lane & 15;
    const int l = p >> 2;
    const int sz = 64 >> l;
    const int start = (16384 - 4 * sz * sz) / 3;   // 0,4096,5120,5376

    float logit = qk[(size_t)t * 384 + 256 + h * 16 + p];
    float mx = logit;
#pragma unroll
    for (int mk = 1; mk <= 8; mk <<= 1) mx = fmaxf(mx, __shfl_xor(mx, mk));
    const float e = __expf(logit - mx);
    float ssum = e;
#pragma unroll
    for (int mk = 1; mk <= 8; mk <<= 1) ssum += __shfl_xor(ssum, mk);
    const float aw = e / ssum;

    const float2 r2 = *(const float2*)(refp + (size_t)t * 8 + l * 2);
    const float2 o2 = *(const float2*)(qk + (size_t)t * 384 + h * 32 + p * 2);
    const float x = r2.x * (float)sz + o2.x - 0.5f;
    const float y = r2.y * (float)sz + o2.y - 0.5f;
    const float x0f = floorf(x), y0f = floorf(y);
    const float wx = x - x0f, wy = y - y0f;
    const int x0 = (int)x0f, y0 = (int)y0f;

    const uint base_tok = (uint)((t / LQ) * LQ + start);

    uint oo[4];
    float ww[4];
#pragma unroll
    for (int cy = 0; cy < 2; cy++) {
        const int yi = y0 + cy;
        const float wyy = cy ? wy : 1.f - wy;
        const bool vy = (yi >= 0) && (yi < sz);
        const int yc = min(max(yi, 0), sz - 1);
#pragma unroll
        for (int cx = 0; cx < 2; cx++) {
            const int xi = x0 + cx;
            const float wxx = cx ? wx : 1.f - wx;
            const bool vx = (xi >= 0) && (xi < sz);
            const int xc = min(max(xi, 0), sz - 1);
            const int j = cy * 2 + cx;
            ww[j] = aw * wxx * wyy * ((vx && vy) ? 1.f : 0.f);
            oo[j] = (base_tok + (uint)(yc * sz + xc)) * 256u + (uint)(h * 32);
        }
    }

    // ---- Phase B ----
    float acc = 0.f;
#pragma unroll
    for (int c = 0; c < 64; c++) {
        const int pp = c >> 2, j = c & 3;
        const uint  so = (uint)__builtin_amdgcn_readlane((int)oo[j], pp);
        const float sw = __int_as_float(
            __builtin_amdgcn_readlane(__float_as_int(ww[j]), pp));
        acc = fmaf(sw, b2f(value[(size_t)so + d]), acc);
    }
    if (lane < 32) outb[(size_t)t * 256 + h * 32 + d] = f2b(acc);
}

// ---------------------------------------------------------------------------
// LayerNorm over 256: out = LN(A + B) * g + b.  One wave per token.
// ---------------------------------------------------------------------------
template <bool A_BF16, bool B_BF16, bool OUT_BF16>
__global__ __launch_bounds__(256) void ln_kernel(
    const void* __restrict__ Av, const void* __restrict__ Bv,
    const float* __restrict__ gamma, const float* __restrict__ beta,
    void* __restrict__ outv)
{
    const int t = blockIdx.x * 4 + (threadIdx.x >> 6);
    const int lane = threadIdx.x & 63;

    float v[4];
    float s = 0.f;
#pragma unroll
    for (int i = 0; i < 4; i++) {
        const int c = lane * 4 + i;
        const float aa = A_BF16 ? b2f(((const bf16*)Av)[(size_t)t * CCH + c])
                                : ((const float*)Av)[(size_t)t * CCH + c];
        const float bb = B_BF16 ? b2f(((const bf16*)Bv)[(size_t)t * CCH + c])
                                : ((const float*)Bv)[(size_t)t * CCH + c];
        v[i] = aa + bb;
        s += v[i];
    }
#pragma unroll
    for (int o = 32; o > 0; o >>= 1) s += __shfl_down(s, o, 64);
    s = __shfl(s, 0, 64);
    const float mean = s * (1.f / 256.f);

    float vs = 0.f;
#pragma unroll
    for (int i = 0; i < 4; i++) { const float dd = v[i] - mean; vs += dd * dd; }
#pragma unroll
    for (int o = 32; o > 0; o >>= 1) vs += __shfl_down(vs, o, 64);
    vs = __shfl(vs, 0, 64);
    const float inv = rsqrtf(vs * (1.f / 256.f) + 1e-5f);

#pragma unroll
    for (int i = 0; i < 4; i++) {
        const int c = lane * 4 + i;
        const float o = (v[i] - mean) * inv * gamma[c] + beta[c];
        if (OUT_BF16) ((bf16*)outv)[(size_t)t * CCH + c] = f2b(o);
        else          ((float*)outv)[(size_t)t * CCH + c] = o;
    }
}

// ---------------------------------------------------------------------------
extern "C" void kernel_launch(void* const* d_in, const int* in_sizes, int n_in,
                              void* d_out, int out_size, void* d_ws, size_t ws_size,
                              hipStream_t stream)
{
    const float* src    = (const float*)d_in[0];
    const float* pos    = (const float*)d_in[1];
    const float* refp   = (const float*)d_in[2];
    const float* w_off  = (const float*)d_in[3];
    const float* b_off  = (const float*)d_in[4];
    const float* w_attn = (const float*)d_in[5];
    const float* b_attn = (const float*)d_in[6];
    const float* w_val  = (const float*)d_in[7];
    const float* b_val  = (const float*)d_in[8];
    const float* w_out  = (const float*)d_in[9];
    const float* b_out  = (const float*)d_in[10];
    const float* g1     = (const float*)d_in[11];
    const float* be1    = (const float*)d_in[12];
    const float* w_ff1  = (const float*)d_in[13];
    const float* b_ff1  = (const float*)d_in[14];
    const float* w_ff2  = (const float*)d_in[15];
    const float* b_ff2  = (const float*)d_in[16];
    const float* g2     = (const float*)d_in[17];
    const float* be2    = (const float*)d_in[18];

    float* outp = (float*)d_out;
    char* ws = (char*)d_ws;

    // Workspace (bytes), peak ~157.6 MB (same budget as prior rounds):
    //   R0 [0,       TT*512)  : q_bf -> attn_o          (bf16)
    //   R1 [TT*512,  TT*1024) : s_bf -> x1b (live->ln2) (bf16)
    //   R2 [TT*1024, TT*2560) : qk_out (f32 TTx384) -> src2 (f32) -> ffh head
    //   R3 [TT*2560, TT*3072) : value (bf16)            -> ffh tail
    //   Y  [TT*3072, TT*3584) : y2b (bf16)
    //   W  [TT*3584, +1.6MB)  : transposed weights + bqk
    bf16*  q_bf   = (bf16*)(ws);
    bf16*  attn_o = (bf16*)(ws);
    bf16*  s_bf   = (bf16*)(ws + (size_t)TT * 512);
    bf16*  x1b    = (bf16*)(ws + (size_t)TT * 512);
    float* qk_out = (float*)(ws + (size_t)TT * 1024);
    float* src2   = (float*)(ws + (size_t)TT * 1024);
    bf16*  ffh    = (bf16*)(ws + (size_t)TT * 1024);   // TT x 1024 bf16 (R2+R3)
    bf16*  value  = (bf16*)(ws + (size_t)TT * 2560);
    bf16*  y2b    = (bf16*)(ws + (size_t)TT * 3072);
    char*  wp     = ws + (size_t)TT * 3584;
    bf16*  wqkT = (bf16*)(wp);                 // 384x256
    bf16*  wvT  = (bf16*)(wp + 196608);        // 256x256
    bf16*  woT  = (bf16*)(wp + 327680);        // 256x256
    bf16*  wf1T = (bf16*)(wp + 458752);        // 1024x256
    bf16*  wf2T = (bf16*)(wp + 983040);        // 256x1024
    float* bqk  = (float*)(wp + 1507328);      // 384 f32

    // --- prep (2 launches) ---
    prep_tokens<<<TT * CCH / 4 / 256, 256, 0, stream>>>(src, pos, q_bf, s_bf);
    prep_weights<<<(753664 + 384 + 255) / 256, 256, 0, stream>>>(
        w_off, w_attn, w_val, w_out, w_ff1, w_ff2, b_off, b_attn,
        wqkT, wvT, woT, wf1T, wf2T, bqk);

    // --- MSDeformAttn ---
    mfma_gemm<false, false><<<dim3(3, TT / 128), 256, 0, stream>>>(
        q_bf, wqkT, bqk, qk_out, TT, 384, 256);
    mfma_gemm<false, true><<<dim3(2, TT / 128), 256, 0, stream>>>(
        s_bf, wvT, b_val, value, TT, 256, 256);
    msda_kernel<<<TT * 2, 256, 0, stream>>>(value, qk_out, refp, attn_o);
    mfma_gemm<false, false><<<dim3(2, TT / 128), 256, 0, stream>>>(
        attn_o, woT, b_out, src2, TT, 256, 256);
    // x1b = bf16(LN(src + src2))
    ln_kernel<false, false, true><<<TT / 4, 256, 0, stream>>>(src, src2, g1, be1, x1b);

    // --- FFN (full M, no chunking) ---
    mfma_gemm<true, true><<<dim3(8, TT / 128), 256, 0, stream>>>(
        x1b, wf1T, b_ff1, ffh, TT, 1024, 256);
    mfma_gemm<false, true><<<dim3(2, TT / 128), 256, 0, stream>>>(
        ffh, wf2T, b_ff2, y2b, TT, 256, 1024);
    // out = LN(x1 + y2)  (both bf16) -> f32
    ln_kernel<true, true, false><<<TT / 4, 256, 0, stream>>>(x1b, y2b, g2, be2, outp);
}

// Round 6
// 414.144 us; speedup vs baseline: 1.5540x; 1.5540x over previous
//
#include <hip/hip_runtime.h>
#include <hip/hip_bf16.h>

typedef __hip_bfloat16 bf16;
typedef __attribute__((ext_vector_type(8))) short short8;
typedef __attribute__((ext_vector_type(4))) float f32x4;

#define NB    8
#define LQ    5440
#define CCH   256
#define NHD   8
#define DFF   1024
#define TT    (NB * LQ)   // 43520 tokens

__device__ __forceinline__ float b2f(bf16 x) { return __bfloat162float(x); }
__device__ __forceinline__ bf16  f2b(float x) { return __float2bfloat16(x); }

// ---------------------------------------------------------------------------
// MFMA bf16 GEMM (register-staged LDS, K+1 prefetch) — round-3/5 proven.
// A: M x K bf16 row-major. BT: N x K bf16 row-major (pre-transposed).
// 256 thr = 4 waves (2x2); tile 128x128; BK=32; 16x16x32 MFMA.
// ---------------------------------------------------------------------------
template <bool RELU, bool OUT_BF16>
__global__ __launch_bounds__(256) void mfma_gemm(
    const bf16* __restrict__ A, const bf16* __restrict__ BT,
    const float* __restrict__ bias, void* __restrict__ Cout,
    int M, int N, int K)
{
    __shared__ bf16 Abuf[128 * 32];
    __shared__ bf16 Bbuf[128 * 32];

    const int tid = threadIdx.x;
    const int wv = tid >> 6;
    const int ln = tid & 63;
    const int lane15 = ln & 15;
    const int quad = ln >> 4;
    const int m0 = blockIdx.y * 128;
    const int n0 = blockIdx.x * 128;
    const int wm = (wv >> 1) * 64;
    const int wn = (wv & 1) * 64;

    const int ar = tid >> 2;           // 0..63: row within 64-row half
    const int ac = (tid & 3) * 8;      // elem col (16B)

    f32x4 acc[4][4];
#pragma unroll
    for (int i = 0; i < 4; i++)
#pragma unroll
        for (int j = 0; j < 4; j++) acc[i][j] = (f32x4){0.f, 0.f, 0.f, 0.f};

    const int KT = K >> 5;
    short8 av[2], bv[2];
#pragma unroll
    for (int j = 0; j < 2; j++) {
        av[j] = *(const short8*)(A  + (size_t)(m0 + j * 64 + ar) * K + ac);
        bv[j] = *(const short8*)(BT + (size_t)(n0 + j * 64 + ar) * K + ac);
    }

    for (int kt = 0; kt < KT; kt++) {
        __syncthreads();
#pragma unroll
        for (int j = 0; j < 2; j++) {
            *(short8*)(Abuf + j * 2048 + tid * 8) = av[j];
            *(short8*)(Bbuf + j * 2048 + tid * 8) = bv[j];
        }
        __syncthreads();
        if (kt + 1 < KT) {
            const int k0 = (kt + 1) << 5;
#pragma unroll
            for (int j = 0; j < 2; j++) {
                av[j] = *(const short8*)(A  + (size_t)(m0 + j * 64 + ar) * K + k0 + ac);
                bv[j] = *(const short8*)(BT + (size_t)(n0 + j * 64 + ar) * K + k0 + ac);
            }
        }
        short8 afrag[4], bfrag[4];
#pragma unroll
        for (int i = 0; i < 4; i++)
            afrag[i] = *(const short8*)(Abuf + (wm + i * 16 + lane15) * 32 + quad * 8);
#pragma unroll
        for (int i = 0; i < 4; i++)
            bfrag[i] = *(const short8*)(Bbuf + (wn + i * 16 + lane15) * 32 + quad * 8);
#pragma unroll
        for (int mi = 0; mi < 4; mi++)
#pragma unroll
            for (int ni = 0; ni < 4; ni++)
                acc[mi][ni] = __builtin_amdgcn_mfma_f32_16x16x32_bf16(
                    afrag[mi], bfrag[ni], acc[mi][ni], 0, 0, 0);
    }

    // Epilogue. C/D layout: col = lane&15, row = quad*4 + reg.
#pragma unroll
    for (int ni = 0; ni < 4; ni++) {
        const int col = n0 + wn + ni * 16 + lane15;
        const float bi = bias[col];
#pragma unroll
        for (int mi = 0; mi < 4; mi++) {
#pragma unroll
            for (int r = 0; r < 4; r++) {
                const int row = m0 + wm + mi * 16 + quad * 4 + r;
                float v = acc[mi][ni][r] + bi;
                if (RELU) v = v > 0.f ? v : 0.f;
                if (OUT_BF16) ((bf16*)Cout)[(size_t)row * N + col] = f2b(v);
                else          ((float*)Cout)[(size_t)row * N + col] = v;
            }
        }
    }
}

// ---------------------------------------------------------------------------
// q_bf = bf16(src+pos); s_bf = bf16(src).
// ---------------------------------------------------------------------------
__global__ __launch_bounds__(256) void prep_tokens(
    const float* __restrict__ src, const float* __restrict__ pos,
    bf16* __restrict__ qb, bf16* __restrict__ sb)
{
    const int i = (blockIdx.x * 256 + threadIdx.x) * 4;
    const float4 s = *(const float4*)(src + i);
    const float4 p = *(const float4*)(pos + i);
    union { bf16 h[4]; ushort4 u; } qo, so;
    qo.h[0] = f2b(s.x + p.x); qo.h[1] = f2b(s.y + p.y);
    qo.h[2] = f2b(s.z + p.z); qo.h[3] = f2b(s.w + p.w);
    so.h[0] = f2b(s.x); so.h[1] = f2b(s.y); so.h[2] = f2b(s.z); so.h[3] = f2b(s.w);
    *(ushort4*)(qb + i) = qo.u;
    *(ushort4*)(sb + i) = so.u;
}

// ---------------------------------------------------------------------------
// All weight transposes + bias concat in ONE launch.
// ---------------------------------------------------------------------------
__global__ __launch_bounds__(256) void prep_weights(
    const float* __restrict__ w_off, const float* __restrict__ w_attn,
    const float* __restrict__ w_val, const float* __restrict__ w_out,
    const float* __restrict__ w_ff1, const float* __restrict__ w_ff2,
    const float* __restrict__ b_off, const float* __restrict__ b_attn,
    bf16* __restrict__ wqkT, bf16* __restrict__ wvT, bf16* __restrict__ woT,
    bf16* __restrict__ wf1T, bf16* __restrict__ wf2T, float* __restrict__ bqk)
{
    int i = blockIdx.x * 256 + threadIdx.x;
    if (i < 65536) {                       // w_off: K=256,N=256
        wqkT[i] = f2b(w_off[(size_t)(i & 255) * 256 + (i >> 8)]);
    } else if ((i -= 65536) < 32768) {     // w_attn: K=256,N=128
        wqkT[65536 + i] = f2b(w_attn[(size_t)(i & 255) * 128 + (i >> 8)]);
    } else if ((i -= 32768) < 65536) {     // w_val
        wvT[i] = f2b(w_val[(size_t)(i & 255) * 256 + (i >> 8)]);
    } else if ((i -= 65536) < 65536) {     // w_out
        woT[i] = f2b(w_out[(size_t)(i & 255) * 256 + (i >> 8)]);
    } else if ((i -= 65536) < 262144) {    // w_ff1: K=256,N=1024 -> WT 1024x256
        wf1T[i] = f2b(w_ff1[(size_t)(i & 255) * 1024 + (i >> 8)]);
    } else if ((i -= 262144) < 262144) {   // w_ff2: K=1024,N=256 -> WT 256x1024
        wf2T[i] = f2b(w_ff2[(size_t)(i & 1023) * 256 + (i >> 10)]);
    } else if ((i -= 262144) < 384) {      // bias concat
        bqk[i] = (i < 256) ? b_off[i] : b_attn[i - 256];
    }
}

// ---------------------------------------------------------------------------
// Deformable sampling v4: two-phase LDS (round-4 structure), fixed.
// Block = 256 thr = 16 units (unit = (token, head)).
// Phase A: 16 lanes/unit, one lane per point: fused softmax (16-lane shfl_xor)
//   + 4 corner (byte-offset, weight) pairs -> LDS, stride padded to 66
//   (66*8B=528B -> adjacent units offset 4 banks; wave's 4 groups read
//    disjoint bank pairs -> conflict-free broadcast).
// Phase B: 16 lanes/unit, 2 channels/lane via one dword load; bf16 pair
//   unpacked by shift/mask (exact); 2 fmac. Packed dword store.
// ---------------------------------------------------------------------------
__global__ __launch_bounds__(256) void msda_kernel(
    const bf16*  __restrict__ value,   // TT x 256 bf16
    const float* __restrict__ qk,      // TT x 384: off 0..255, logits 256..383
    const float* __restrict__ refp,    // TT x 8
    bf16* __restrict__ outb)           // TT x 256 bf16
{
    __shared__ uint2 s_ow[16 * 66];    // per unit: 16 points x 4 corners, pad 2

    const int u_local = threadIdx.x >> 4;        // 0..15
    const int lane16 = threadIdx.x & 15;
    const int unit = blockIdx.x * 16 + u_local;
    const int t = unit >> 3;
    const int h = unit & 7;

    // ---- Phase A: one point per lane ----
    {
        const int p = lane16;
        const int l = p >> 2;
        const int sz = 64 >> l;
        const int start = (16384 - 4 * sz * sz) / 3;   // 0,4096,5120,5376

        const float logit = qk[(size_t)t * 384 + 256 + h * 16 + p];
        float mx = logit;
#pragma unroll
        for (int mk = 1; mk <= 8; mk <<= 1) mx = fmaxf(mx, __shfl_xor(mx, mk));
        const float e = __expf(logit - mx);
        float ssum = e;
#pragma unroll
        for (int mk = 1; mk <= 8; mk <<= 1) ssum += __shfl_xor(ssum, mk);
        const float aw = e / ssum;

        const float2 r2 = *(const float2*)(refp + (size_t)t * 8 + l * 2);
        const float2 o2 = *(const float2*)(qk + (size_t)t * 384 + h * 32 + p * 2);
        const float x = r2.x * (float)sz + o2.x - 0.5f;
        const float y = r2.y * (float)sz + o2.y - 0.5f;
        const float x0f = floorf(x), y0f = floorf(y);
        const float wx = x - x0f, wy = y - y0f;
        const int x0 = (int)x0f, y0 = (int)y0f;

        const uint base_tok = (uint)((t / LQ) * LQ + start);
        uint2* dst = s_ow + u_local * 66 + p * 4;
#pragma unroll
        for (int cy = 0; cy < 2; cy++) {
            const int yi = y0 + cy;
            const float wyy = cy ? wy : 1.f - wy;
            const bool vy = (yi >= 0) && (yi < sz);
            const int yc = min(max(yi, 0), sz - 1);
#pragma unroll
            for (int cx = 0; cx < 2; cx++) {
                const int xi = x0 + cx;
                const float wxx = cx ? wx : 1.f - wx;
                const bool vx = (xi >= 0) && (xi < sz);
                const int xc = min(max(xi, 0), sz - 1);
                const float w = aw * wxx * wyy * ((vx && vy) ? 1.f : 0.f);
                // byte offset of this corner's row segment for head h
                const uint offb = ((base_tok + (uint)(yc * sz + xc)) * 256u
                                   + (uint)(h * 32)) * 2u;
                dst[cy * 2 + cx] = make_uint2(offb, __float_as_uint(w));
            }
        }
    }
    __syncthreads();

    // ---- Phase B: 2 channels per lane ----
    const char* vbase = (const char*)value + lane16 * 4;
    const uint2* po = s_ow + u_local * 66;
    float acc0 = 0.f, acc1 = 0.f;
#pragma unroll
    for (int c = 0; c < 64; c++) {
        const uint2 ow = po[c];
        const uint dv = *(const uint*)(vbase + ow.x);
        const float w = __uint_as_float(ow.y);
        acc0 = fmaf(w, __uint_as_float(dv << 16), acc0);
        acc1 = fmaf(w, __uint_as_float(dv & 0xffff0000u), acc1);
    }
    union { bf16 hh[2]; uint u; } pk;
    pk.hh[0] = f2b(acc0); pk.hh[1] = f2b(acc1);
    *(uint*)((char*)outb + ((size_t)t * 256 + h * 32) * 2 + lane16 * 4) = pk.u;
}

// ---------------------------------------------------------------------------
// LayerNorm over 256: out = LN(A + B) * g + b.  One wave per token.
// ---------------------------------------------------------------------------
template <bool A_BF16, bool B_BF16, bool OUT_BF16>
__global__ __launch_bounds__(256) void ln_kernel(
    const void* __restrict__ Av, const void* __restrict__ Bv,
    const float* __restrict__ gamma, const float* __restrict__ beta,
    void* __restrict__ outv)
{
    const int t = blockIdx.x * 4 + (threadIdx.x >> 6);
    const int lane = threadIdx.x & 63;

    float v[4];
    float s = 0.f;
#pragma unroll
    for (int i = 0; i < 4; i++) {
        const int c = lane * 4 + i;
        const float aa = A_BF16 ? b2f(((const bf16*)Av)[(size_t)t * CCH + c])
                                : ((const float*)Av)[(size_t)t * CCH + c];
        const float bb = B_BF16 ? b2f(((const bf16*)Bv)[(size_t)t * CCH + c])
                                : ((const float*)Bv)[(size_t)t * CCH + c];
        v[i] = aa + bb;
        s += v[i];
    }
#pragma unroll
    for (int o = 32; o > 0; o >>= 1) s += __shfl_down(s, o, 64);
    s = __shfl(s, 0, 64);
    const float mean = s * (1.f / 256.f);

    float vs = 0.f;
#pragma unroll
    for (int i = 0; i < 4; i++) { const float dd = v[i] - mean; vs += dd * dd; }
#pragma unroll
    for (int o = 32; o > 0; o >>= 1) vs += __shfl_down(vs, o, 64);
    vs = __shfl(vs, 0, 64);
    const float inv = rsqrtf(vs * (1.f / 256.f) + 1e-5f);

#pragma unroll
    for (int i = 0; i < 4; i++) {
        const int c = lane * 4 + i;
        const float o = (v[i] - mean) * inv * gamma[c] + beta[c];
        if (OUT_BF16) ((bf16*)outv)[(size_t)t * CCH + c] = f2b(o);
        else          ((float*)outv)[(size_t)t * CCH + c] = o;
    }
}

// ---------------------------------------------------------------------------
extern "C" void kernel_launch(void* const* d_in, const int* in_sizes, int n_in,
                              void* d_out, int out_size, void* d_ws, size_t ws_size,
                              hipStream_t stream)
{
    const float* src    = (const float*)d_in[0];
    const float* pos    = (const float*)d_in[1];
    const float* refp   = (const float*)d_in[2];
    const float* w_off  = (const float*)d_in[3];
    const float* b_off  = (const float*)d_in[4];
    const float* w_attn = (const float*)d_in[5];
    const float* b_attn = (const float*)d_in[6];
    const float* w_val  = (const float*)d_in[7];
    const float* b_val  = (const float*)d_in[8];
    const float* w_out  = (const float*)d_in[9];
    const float* b_out  = (const float*)d_in[10];
    const float* g1     = (const float*)d_in[11];
    const float* be1    = (const float*)d_in[12];
    const float* w_ff1  = (const float*)d_in[13];
    const float* b_ff1  = (const float*)d_in[14];
    const float* w_ff2  = (const float*)d_in[15];
    const float* b_ff2  = (const float*)d_in[16];
    const float* g2     = (const float*)d_in[17];
    const float* be2    = (const float*)d_in[18];

    float* outp = (float*)d_out;
    char* ws = (char*)d_ws;

    // Workspace (bytes), peak ~157.6 MB:
    //   R0 [0,       TT*512)  : q_bf -> attn_o          (bf16)
    //   R1 [TT*512,  TT*1024) : s_bf -> x1b (live->ln2) (bf16)
    //   R2 [TT*1024, TT*2560) : qk_out (f32 TTx384) -> src2 (f32) -> ffh head
    //   R3 [TT*2560, TT*3072) : value (bf16)            -> ffh tail
    //   Y  [TT*3072, TT*3584) : y2b (bf16)
    //   W  [TT*3584, +1.6MB)  : transposed weights + bqk
    bf16*  q_bf   = (bf16*)(ws);
    bf16*  attn_o = (bf16*)(ws);
    bf16*  s_bf   = (bf16*)(ws + (size_t)TT * 512);
    bf16*  x1b    = (bf16*)(ws + (size_t)TT * 512);
    float* qk_out = (float*)(ws + (size_t)TT * 1024);
    float* src2   = (float*)(ws + (size_t)TT * 1024);
    bf16*  ffh    = (bf16*)(ws + (size_t)TT * 1024);   // TT x 1024 bf16 (R2+R3)
    bf16*  value  = (bf16*)(ws + (size_t)TT * 2560);
    bf16*  y2b    = (bf16*)(ws + (size_t)TT * 3072);
    char*  wp     = ws + (size_t)TT * 3584;
    bf16*  wqkT = (bf16*)(wp);                 // 384x256
    bf16*  wvT  = (bf16*)(wp + 196608);        // 256x256
    bf16*  woT  = (bf16*)(wp + 327680);        // 256x256
    bf16*  wf1T = (bf16*)(wp + 458752);        // 1024x256
    bf16*  wf2T = (bf16*)(wp + 983040);        // 256x1024
    float* bqk  = (float*)(wp + 1507328);      // 384 f32

    // --- prep (2 launches) ---
    prep_tokens<<<TT * CCH / 4 / 256, 256, 0, stream>>>(src, pos, q_bf, s_bf);
    prep_weights<<<(753664 + 384 + 255) / 256, 256, 0, stream>>>(
        w_off, w_attn, w_val, w_out, w_ff1, w_ff2, b_off, b_attn,
        wqkT, wvT, woT, wf1T, wf2T, bqk);

    // --- MSDeformAttn ---
    mfma_gemm<false, false><<<dim3(3, TT / 128), 256, 0, stream>>>(
        q_bf, wqkT, bqk, qk_out, TT, 384, 256);
    mfma_gemm<false, true><<<dim3(2, TT / 128), 256, 0, stream>>>(
        s_bf, wvT, b_val, value, TT, 256, 256);
    msda_kernel<<<TT / 2, 256, 0, stream>>>(value, qk_out, refp, attn_o);
    mfma_gemm<false, false><<<dim3(2, TT / 128), 256, 0, stream>>>(
        attn_o, woT, b_out, src2, TT, 256, 256);
    // x1b = bf16(LN(src + src2))
    ln_kernel<false, false, true><<<TT / 4, 256, 0, stream>>>(src, src2, g1, be1, x1b);

    // --- FFN (full M) ---
    mfma_gemm<true, true><<<dim3(8, TT / 128), 256, 0, stream>>>(
        x1b, wf1T, b_ff1, ffh, TT, 1024, 256);
    mfma_gemm<false, true><<<dim3(2, TT / 128), 256, 0, stream>>>(
        ffh, wf2T, b_ff2, y2b, TT, 256, 1024);
    // out = LN(x1 + y2)  (both bf16) -> f32
    ln_kernel<true, true, false><<<TT / 4, 256, 0, stream>>>(x1b, y2b, g2, be2, outp);
}